// Round 1
// baseline (764.687 us; speedup 1.0000x reference)
//
#include <hip/hip_runtime.h>

// GCN: 2x GCNConv (5->16->32) + global mean pool + linear head.
// Restructured: agg[i] = dinv[i] * (sum_{e:dst=i} hs[src] + hs[i]),  hs = dinv * (x@W)
// Self-loops folded into accumulator init; norm folded into pre/post scaling.

#define BLK 256

__global__ void k_degree(const int* __restrict__ dst, int E, int* __restrict__ deg) {
    int e = blockIdx.x * blockDim.x + threadIdx.x;
    if (e < E) atomicAdd(&deg[dst[e]], 1);
}

// dinv = rsqrt(deg+1); hs1 = dinv * (x @ W1); agg1 init = hs1 (self-loop)
__global__ void k_lin1(const float* __restrict__ x, const float* __restrict__ W1,
                       const int* __restrict__ deg, float* __restrict__ dinv,
                       float* __restrict__ hs1, float* __restrict__ agg1, int N) {
    __shared__ float sW[80];
    if (threadIdx.x < 80) sW[threadIdx.x] = W1[threadIdx.x];
    __syncthreads();
    int i = blockIdx.x * blockDim.x + threadIdx.x;
    if (i >= N) return;
    float di = rsqrtf((float)(deg[i] + 1));   // +1 self-loop; always > 0
    dinv[i] = di;
    float xv[5];
#pragma unroll
    for (int d = 0; d < 5; ++d) xv[d] = x[i * 5 + d];
    float4* hs4 = (float4*)(hs1 + i * 16);
    float4* ag4 = (float4*)(agg1 + i * 16);
#pragma unroll
    for (int q = 0; q < 4; ++q) {
        float4 v;
        float* vp = (float*)&v;
#pragma unroll
        for (int r = 0; r < 4; ++r) {
            int k = q * 4 + r;
            float h = 0.f;
#pragma unroll
            for (int d = 0; d < 5; ++d) h = fmaf(xv[d], sW[d * 16 + k], h);
            vp[r] = h * di;
        }
        hs4[q] = v;
        ag4[q] = v;
    }
}

// thread per (edge, k): agg1[dst*16+k] += hs1[src*16+k]
__global__ void k_scatter16(const int* __restrict__ src, const int* __restrict__ dst,
                            const float* __restrict__ hs, float* __restrict__ agg, int E) {
    int tid = blockIdx.x * blockDim.x + threadIdx.x;
    int e = tid >> 4;
    int k = tid & 15;
    if (e >= E) return;
    int s = src[e], d = dst[e];
    atomicAdd(&agg[d * 16 + k], hs[s * 16 + k]);
}

// h1 = relu(dinv*agg1 + b1); hs2 = dinv * (h1 @ W2); agg2 init = hs2
__global__ void k_lin2(const float* __restrict__ agg1, const float* __restrict__ dinv,
                       const float* __restrict__ W2, const float* __restrict__ b1,
                       float* __restrict__ hs2, float* __restrict__ agg2, int N) {
    __shared__ float sW[512];
    __shared__ float sb[16];
    for (int t = threadIdx.x; t < 512; t += blockDim.x) sW[t] = W2[t];
    if (threadIdx.x < 16) sb[threadIdx.x] = b1[threadIdx.x];
    __syncthreads();
    int i = blockIdx.x * blockDim.x + threadIdx.x;
    if (i >= N) return;
    float di = dinv[i];
    float h[16];
    const float4* a4 = (const float4*)(agg1 + i * 16);
#pragma unroll
    for (int q = 0; q < 4; ++q) {
        float4 v = a4[q];
        float* vp = (float*)&v;
#pragma unroll
        for (int r = 0; r < 4; ++r) h[q * 4 + r] = fmaxf(fmaf(di, vp[r], sb[q * 4 + r]), 0.f);
    }
    float4* h4 = (float4*)(hs2 + i * 32);
    float4* g4 = (float4*)(agg2 + i * 32);
#pragma unroll
    for (int q = 0; q < 8; ++q) {
        float4 v;
        float* vp = (float*)&v;
#pragma unroll
        for (int r = 0; r < 4; ++r) {
            int j = q * 4 + r;
            float acc = 0.f;
#pragma unroll
            for (int k = 0; k < 16; ++k) acc = fmaf(h[k], sW[k * 32 + j], acc);
            vp[r] = acc * di;
        }
        h4[q] = v;
        g4[q] = v;
    }
}

// thread per (edge, j): agg2[dst*32+j] += hs2[src*32+j]
__global__ void k_scatter32(const int* __restrict__ src, const int* __restrict__ dst,
                            const float* __restrict__ hs, float* __restrict__ agg, int E) {
    int tid = blockIdx.x * blockDim.x + threadIdx.x;
    int e = tid >> 5;
    int j = tid & 31;
    if (e >= E) return;
    int s = src[e], d = dst[e];
    atomicAdd(&agg[d * 32 + j], hs[s * 32 + j]);
}

// h2 = relu(dinv*agg2 + b2); per-node contrib = h2 . fcW; pool[batch[i]] += contrib
__global__ void k_final(const float* __restrict__ agg2, const float* __restrict__ dinv,
                        const float* __restrict__ b2, const float* __restrict__ fcW,
                        const int* __restrict__ batch, float* __restrict__ pool,
                        int* __restrict__ gcnt, int N) {
    __shared__ float sb[32], sf[32];
    if (threadIdx.x < 32) {
        sb[threadIdx.x] = b2[threadIdx.x];
        sf[threadIdx.x] = fcW[threadIdx.x];
    }
    __syncthreads();
    int tid = blockIdx.x * blockDim.x + threadIdx.x;
    int i = tid >> 5;
    int j = tid & 31;
    if (i >= N) return;
    float di = dinv[i];
    float h = fmaxf(fmaf(di, agg2[i * 32 + j], sb[j]), 0.f);
    float c = h * sf[j];
#pragma unroll
    for (int off = 16; off; off >>= 1) c += __shfl_xor(c, off, 32);
    if (j == 0) {
        int b = batch[i];
        atomicAdd(&pool[b], c);
        atomicAdd(&gcnt[b], 1);
    }
}

__global__ void k_out(const float* __restrict__ pool, const int* __restrict__ gcnt,
                      const float* __restrict__ fcb, float* __restrict__ out, int G) {
    int g = blockIdx.x * blockDim.x + threadIdx.x;
    if (g < G) out[g] = pool[g] / fmaxf((float)gcnt[g], 1.f) + fcb[0];
}

extern "C" void kernel_launch(void* const* d_in, const int* in_sizes, int n_in,
                              void* d_out, int out_size, void* d_ws, size_t ws_size,
                              hipStream_t stream) {
    const float* x    = (const float*)d_in[0];
    const int*   ei   = (const int*)d_in[1];
    const int*   batch= (const int*)d_in[2];
    const float* W1   = (const float*)d_in[3];
    const float* b1   = (const float*)d_in[4];
    const float* W2   = (const float*)d_in[5];
    const float* b2   = (const float*)d_in[6];
    const float* fcW  = (const float*)d_in[7];
    const float* fcb  = (const float*)d_in[8];
    float* out = (float*)d_out;

    const int N = in_sizes[0] / 5;
    const int E = in_sizes[1] / 2;
    const int G = out_size;  // 1024

    const int* src = ei;
    const int* dst = ei + E;

    // workspace carve (bytes; all offsets multiples of 16)
    char* ws = (char*)d_ws;
    int*   deg  = (int*)  (ws);                         // N ints
    float* dinv = (float*)(ws + (size_t)4 * N);         // N
    float* hs1  = (float*)(ws + (size_t)8 * N);         // 16N
    float* agg1 = (float*)(ws + (size_t)72 * N);        // 16N
    float* hs2  = (float*)(ws + (size_t)136 * N);       // 32N
    float* agg2 = (float*)(ws + (size_t)264 * N);       // 32N
    float* pool = (float*)(ws + (size_t)392 * N);       // G
    int*   gcnt = (int*)  (ws + (size_t)392 * N + 4 * G); // G

    // zero the accumulators that are atomically accumulated (every call)
    hipMemsetAsync(deg, 0, (size_t)4 * N, stream);
    hipMemsetAsync(pool, 0, (size_t)8 * G, stream);  // pool + gcnt contiguous

    k_degree<<<(E + BLK - 1) / BLK, BLK, 0, stream>>>(dst, E, deg);
    k_lin1<<<(N + BLK - 1) / BLK, BLK, 0, stream>>>(x, W1, deg, dinv, hs1, agg1, N);
    {
        long long T = (long long)E * 16;
        k_scatter16<<<(int)((T + BLK - 1) / BLK), BLK, 0, stream>>>(src, dst, hs1, agg1, E);
    }
    k_lin2<<<(N + BLK - 1) / BLK, BLK, 0, stream>>>(agg1, dinv, W2, b1, hs2, agg2, N);
    {
        long long T = (long long)E * 32;
        k_scatter32<<<(int)((T + BLK - 1) / BLK), BLK, 0, stream>>>(src, dst, hs2, agg2, E);
    }
    {
        long long T = (long long)N * 32;
        k_final<<<(int)((T + BLK - 1) / BLK), BLK, 0, stream>>>(agg2, dinv, b2, fcW, batch, pool, gcnt, N);
    }
    k_out<<<(G + BLK - 1) / BLK, BLK, 0, stream>>>(pool, gcnt, fcb, out, G);
}

// Round 2
// 576.242 us; speedup vs baseline: 1.3270x; 1.3270x over previous
//
#include <hip/hip_runtime.h>

// GCN: 2x GCNConv (5->16->32) + global mean pool + linear head.
// Algebraic restructuring: @W commutes with segment_sum, so aggregate in the
// INPUT dim of each layer (5 then 16 floats/edge) and apply the weight matrix
// after aggregation. Self-loops folded into accumulator init; symmetric norm
// folded into pre-scale (dinv[src]) and post-scale (dinv[dst]).

#define BLK 256

__global__ void k_degree(const int* __restrict__ dst, int E, int* __restrict__ deg) {
    int e = blockIdx.x * blockDim.x + threadIdx.x;
    if (e < E) atomicAdd(&deg[dst[e]], 1);
}

// dinv = rsqrt(deg+1); sx = dinv * x (5-dim); aggx init = sx (self-loop)
__global__ void k_prep(const float* __restrict__ x, const int* __restrict__ deg,
                       float* __restrict__ dinv, float* __restrict__ sx,
                       float* __restrict__ aggx, int N) {
    int i = blockIdx.x * blockDim.x + threadIdx.x;
    if (i >= N) return;
    float di = rsqrtf((float)(deg[i] + 1));
    dinv[i] = di;
#pragma unroll
    for (int d = 0; d < 5; ++d) {
        float v = x[i * 5 + d] * di;
        sx[i * 5 + d] = v;
        aggx[i * 5 + d] = v;
    }
}

// thread per (edge, k) with k in [0,8), active k<5: aggx[d*5+k] += sx[s*5+k]
__global__ void k_scatter5(const int* __restrict__ src, const int* __restrict__ dst,
                           const float* __restrict__ sx, float* __restrict__ aggx, int E) {
    int tid = blockIdx.x * blockDim.x + threadIdx.x;
    int e = tid >> 3;
    int k = tid & 7;
    if (e >= E || k >= 5) return;
    int s = src[e], d = dst[e];
    atomicAdd(&aggx[d * 5 + k], sx[s * 5 + k]);
}

// h1 = relu(dinv*(aggx@W1) + b1); g = dinv*h1 (16-dim); aggg init = g
__global__ void k_lin1(const float* __restrict__ aggx, const float* __restrict__ dinv,
                       const float* __restrict__ W1, const float* __restrict__ b1,
                       float* __restrict__ g, float* __restrict__ aggg, int N) {
    __shared__ float sW[80], sb[16];
    if (threadIdx.x < 80) sW[threadIdx.x] = W1[threadIdx.x];
    if (threadIdx.x < 16) sb[threadIdx.x] = b1[threadIdx.x];
    __syncthreads();
    int i = blockIdx.x * blockDim.x + threadIdx.x;
    if (i >= N) return;
    float di = dinv[i];
    float a[5];
#pragma unroll
    for (int d = 0; d < 5; ++d) a[d] = aggx[i * 5 + d];
    float4* g4 = (float4*)(g + i * 16);
    float4* ag4 = (float4*)(aggg + i * 16);
#pragma unroll
    for (int q = 0; q < 4; ++q) {
        float4 v;
        float* vp = (float*)&v;
#pragma unroll
        for (int r = 0; r < 4; ++r) {
            int k = q * 4 + r;
            float h = 0.f;
#pragma unroll
            for (int d = 0; d < 5; ++d) h = fmaf(a[d], sW[d * 16 + k], h);
            h = fmaxf(fmaf(di, h, sb[k]), 0.f);
            vp[r] = h * di;
        }
        g4[q] = v;
        ag4[q] = v;
    }
}

// thread per (edge, k): aggg[d*16+k] += g[s*16+k]
__global__ void k_scatter16(const int* __restrict__ src, const int* __restrict__ dst,
                            const float* __restrict__ g, float* __restrict__ aggg, int E) {
    int tid = blockIdx.x * blockDim.x + threadIdx.x;
    int e = tid >> 4;
    int k = tid & 15;
    if (e >= E) return;
    int s = src[e], d = dst[e];
    atomicAdd(&aggg[d * 16 + k], g[s * 16 + k]);
}

// thread per node: h2 = relu(dinv*(aggg@W2) + b2) (32-dim); c = h2 . fcW;
// pool[batch[i]] += c; gcnt[batch[i]] += 1
__global__ void k_fin(const float* __restrict__ aggg, const float* __restrict__ dinv,
                      const float* __restrict__ W2, const float* __restrict__ b2,
                      const float* __restrict__ fcW, const int* __restrict__ batch,
                      float* __restrict__ pool, int* __restrict__ gcnt, int N) {
    __shared__ float sW[512], sb[32], sf[32];
    for (int t = threadIdx.x; t < 512; t += blockDim.x) sW[t] = W2[t];
    if (threadIdx.x < 32) {
        sb[threadIdx.x] = b2[threadIdx.x];
        sf[threadIdx.x] = fcW[threadIdx.x];
    }
    __syncthreads();
    int i = blockIdx.x * blockDim.x + threadIdx.x;
    if (i >= N) return;
    float di = dinv[i];
    float a[16];
    const float4* a4 = (const float4*)(aggg + i * 16);
#pragma unroll
    for (int q = 0; q < 4; ++q) {
        float4 v = a4[q];
        a[q * 4 + 0] = v.x; a[q * 4 + 1] = v.y; a[q * 4 + 2] = v.z; a[q * 4 + 3] = v.w;
    }
    float c = 0.f;
#pragma unroll
    for (int j = 0; j < 32; ++j) {
        float acc = 0.f;
#pragma unroll
        for (int k = 0; k < 16; ++k) acc = fmaf(a[k], sW[k * 32 + j], acc);
        float h = fmaxf(fmaf(di, acc, sb[j]), 0.f);
        c = fmaf(h, sf[j], c);
    }
    int b = batch[i];
    atomicAdd(&pool[b], c);
    atomicAdd(&gcnt[b], 1);
}

__global__ void k_out(const float* __restrict__ pool, const int* __restrict__ gcnt,
                      const float* __restrict__ fcb, float* __restrict__ out, int G) {
    int gI = blockIdx.x * blockDim.x + threadIdx.x;
    if (gI < G) out[gI] = pool[gI] / fmaxf((float)gcnt[gI], 1.f) + fcb[0];
}

extern "C" void kernel_launch(void* const* d_in, const int* in_sizes, int n_in,
                              void* d_out, int out_size, void* d_ws, size_t ws_size,
                              hipStream_t stream) {
    const float* x    = (const float*)d_in[0];
    const int*   ei   = (const int*)d_in[1];
    const int*   batch= (const int*)d_in[2];
    const float* W1   = (const float*)d_in[3];
    const float* b1   = (const float*)d_in[4];
    const float* W2   = (const float*)d_in[5];
    const float* b2   = (const float*)d_in[6];
    const float* fcW  = (const float*)d_in[7];
    const float* fcb  = (const float*)d_in[8];
    float* out = (float*)d_out;

    const int N = in_sizes[0] / 5;
    const int E = in_sizes[1] / 2;
    const int G = out_size;  // 1024

    const int* src = ei;
    const int* dst = ei + E;

    // workspace carve (bytes; N is a multiple of 16 so all offsets 16B-aligned)
    char* ws = (char*)d_ws;
    int*   deg  = (int*)  (ws);                           // N
    float* dinv = (float*)(ws + (size_t)4 * N);           // N
    float* sx   = (float*)(ws + (size_t)8 * N);           // 5N
    float* aggx = (float*)(ws + (size_t)28 * N);          // 5N
    float* g    = (float*)(ws + (size_t)48 * N);          // 16N
    float* aggg = (float*)(ws + (size_t)112 * N);         // 16N
    float* pool = (float*)(ws + (size_t)176 * N);         // G
    int*   gcnt = (int*)  (ws + (size_t)176 * N + 4 * G); // G

    hipMemsetAsync(deg, 0, (size_t)4 * N, stream);
    hipMemsetAsync(pool, 0, (size_t)8 * G, stream);  // pool + gcnt contiguous

    k_degree<<<(E + BLK - 1) / BLK, BLK, 0, stream>>>(dst, E, deg);
    k_prep<<<(N + BLK - 1) / BLK, BLK, 0, stream>>>(x, deg, dinv, sx, aggx, N);
    {
        long long T = (long long)E * 8;
        k_scatter5<<<(int)((T + BLK - 1) / BLK), BLK, 0, stream>>>(src, dst, sx, aggx, E);
    }
    k_lin1<<<(N + BLK - 1) / BLK, BLK, 0, stream>>>(aggx, dinv, W1, b1, g, aggg, N);
    {
        long long T = (long long)E * 16;
        k_scatter16<<<(int)((T + BLK - 1) / BLK), BLK, 0, stream>>>(src, dst, g, aggg, E);
    }
    k_fin<<<(N + BLK - 1) / BLK, BLK, 0, stream>>>(aggg, dinv, W2, b2, fcW, batch, pool, gcnt, N);
    k_out<<<(G + BLK - 1) / BLK, BLK, 0, stream>>>(pool, gcnt, fcb, out, G);
}